// Round 13
// baseline (263.506 us; speedup 1.0000x reference)
//
#include <hip/hip_runtime.h>
#include <hip/hip_bf16.h>
#include <math.h>

// GraphSAGE: 4 layers on N=100000 nodes, E=1600000 edges.
// Round 13: uint4 (16B/lane) fp8 gather loads -> 8/16 rows per wave-load,
// fp8 x-table for layer-1 gather. Self (prev) paths stay bf16.

typedef unsigned char u8;
typedef unsigned short u16;
typedef unsigned int u32;
typedef __attribute__((ext_vector_type(2))) float f32x2;
typedef __attribute__((ext_vector_type(4))) float f32x4;
typedef __attribute__((ext_vector_type(8))) short s16x8;

#define BCAP 4096  // staging capacity per bucket (mean 2048, +45 sigma)

__device__ __forceinline__ float b2f(u16 u) {
  union { float f; u32 i; } v; v.i = ((u32)u) << 16; return v.f;
}
__device__ __forceinline__ u16 f2b(float f) {
  union { float f; u32 u; } v; v.f = f;
  u32 r = v.u + 0x7fffu + ((v.u >> 16) & 1u);   // RTN-even
  return (u16)(r >> 16);
}

// ---------------- CSR build ----------------
__global__ __launch_bounds__(512) void bucketize(const int* __restrict__ ei,
                                                 int* __restrict__ gcur,
                                                 u32* __restrict__ staging,
                                                 int E, int B) {
  __shared__ u32 vals[8192];
  __shared__ u16 bkt[8192];
  __shared__ int hist[1024], ofs[1024], curx[1024], gbase[1024];
  __shared__ int wsum[512];

  const int t = threadIdx.x;
  const int base = blockIdx.x * 8192;
  const int cnt = min(8192, E - base);

  for (int b = t; b < 1024; b += 512) hist[b] = 0;
  __syncthreads();

  for (int k = t; k < cnt; k += 512) {
    int d = ei[E + base + k];
    atomicAdd(&hist[d >> 7], 1);
  }
  __syncthreads();

  int a0 = hist[2 * t], a1 = hist[2 * t + 1];
  int s = a0 + a1;
  wsum[t] = s;
  __syncthreads();
  for (int off = 1; off < 512; off <<= 1) {
    int add = (t >= off) ? wsum[t - off] : 0;
    __syncthreads();
    wsum[t] += add;
    __syncthreads();
  }
  int excl = wsum[t] - s;
  ofs[2 * t] = excl;
  ofs[2 * t + 1] = excl + a0;
  __syncthreads();

  for (int b = t; b < B; b += 512) {
    int c = hist[b];
    gbase[b] = c ? atomicAdd(&gcur[b], c) : 0;
    curx[b] = ofs[b];
  }
  __syncthreads();

  for (int k = t; k < cnt; k += 512) {
    int sv = ei[base + k];
    int d = ei[E + base + k];
    int b = d >> 7;
    u32 val = (u32)sv | ((u32)(d & 127) << 17);
    int lpos = atomicAdd(&curx[b], 1);
    vals[lpos] = val;
    bkt[lpos] = (u16)b;
  }
  __syncthreads();

  for (int i = t; i < cnt; i += 512) {
    int b = bkt[i];
    staging[(size_t)b * BCAP + gbase[b] + (i - ofs[b])] = vals[i];
  }
}

__global__ __launch_bounds__(512) void scan_tiny(const int* __restrict__ gcur,
                                                 int* __restrict__ bucket_base,
                                                 int* __restrict__ rowptr,
                                                 int N, int E) {
  __shared__ int wsum[512];
  const int t = threadIdx.x;
  int c0 = gcur[2 * t];
  int c1 = gcur[2 * t + 1];
  int s = c0 + c1;
  wsum[t] = s;
  __syncthreads();
  for (int off = 1; off < 512; off <<= 1) {
    int add = (t >= off) ? wsum[t - off] : 0;
    __syncthreads();
    wsum[t] += add;
    __syncthreads();
  }
  int excl = wsum[t] - s;
  bucket_base[2 * t] = excl;
  bucket_base[2 * t + 1] = excl + c0;
  if (t == 511) bucket_base[1024] = wsum[511];
  if (t == 0) rowptr[N] = E;
}

__global__ __launch_bounds__(256) void place(const u32* __restrict__ staging,
                                             const int* __restrict__ bucket_base,
                                             int* __restrict__ rowptr,
                                             int* __restrict__ csr, int N) {
  __shared__ int cnt[128], excl[128], cur[128], sc[128];
  const int t = threadIdx.x;
  const int node0 = blockIdx.x << 7;
  const int nn = min(128, N - node0);
  if (t < 128) { cnt[t] = 0; cur[t] = 0; }
  __syncthreads();
  const int rstart = bucket_base[blockIdx.x];
  const int ec = bucket_base[blockIdx.x + 1] - rstart;
  const u32* slice = staging + (size_t)blockIdx.x * BCAP;
  for (int i = t; i < ec; i += 256)
    atomicAdd(&cnt[slice[i] >> 17], 1);
  __syncthreads();
  if (t < 128) sc[t] = cnt[t];
  __syncthreads();
  for (int off = 1; off < 128; off <<= 1) {
    int add = (t < 128 && t >= off) ? sc[t - off] : 0;
    __syncthreads();
    if (t < 128) sc[t] += add;
    __syncthreads();
  }
  if (t < 128) excl[t] = sc[t] - cnt[t];
  if (t < nn) rowptr[node0 + t] = rstart + excl[t];
  __syncthreads();
  for (int i = t; i < ec; i += 256) {
    u32 v = slice[i];
    int nl = v >> 17;
    int src = v & 0x1FFFF;
    int tk = atomicAdd(&cur[nl], 1);
    csr[rstart + excl[nl] + tk] = src;
  }
}

// ---------------- conversions (fused) ----------------
__global__ __launch_bounds__(256) void cvt_all(const float* __restrict__ x,
                                               u16* __restrict__ xb,
                                               u32* __restrict__ x8,  // fp8 x table
                                               int total4,
                                               const float* __restrict__ W1l,
                                               const float* __restrict__ W1r,
                                               const float* __restrict__ W2l,
                                               const float* __restrict__ W2r,
                                               u16* __restrict__ wt1,
                                               u16* __restrict__ wt2) {
  int i = blockIdx.x * 256 + threadIdx.x;
  if (i < total4) {
    float4 v = *(const float4*)(x + (size_t)i * 4);
    u32 lo = (u32)f2b(v.x) | ((u32)f2b(v.y) << 16);
    u32 hi = (u32)f2b(v.z) | ((u32)f2b(v.w) << 16);
    uint2 o; o.x = lo; o.y = hi;
    *(uint2*)(xb + (size_t)i * 4) = o;
    u32 pk = __builtin_amdgcn_cvt_pk_fp8_f32(v.x, v.y, 0, false);
    pk = __builtin_amdgcn_cvt_pk_fp8_f32(v.z, v.w, pk, true);
    x8[i] = pk;
    return;
  }
  int j = i - total4;
  if (j < 16384) {                 // Wt1: 128 x 128
    int jj = j >> 7, k = j & 127;
    float v = (k < 64) ? W1l[k * 128 + jj] : W1r[(k - 64) * 128 + jj];
    wt1[jj * 128 + k] = f2b(v);
  } else if (j < 16384 + 32768) {  // Wt2: 128 x 256
    int i2 = j - 16384;
    int jj = i2 >> 8, k = i2 & 255;
    float v = (k < 128) ? W2l[k * 128 + jj] : W2r[(k - 128) * 128 + jj];
    wt2[jj * 256 + k] = f2b(v);
  }
}

// ---------------- fp8 gather means ----------------
// accumulate 16 fp8 (uint4) into 8 f32x2
#define F8ACC16(v)                                                     \
  a0 += __builtin_amdgcn_cvt_pk_f32_fp8((v).x, false);                 \
  a1 += __builtin_amdgcn_cvt_pk_f32_fp8((v).x, true);                  \
  a2 += __builtin_amdgcn_cvt_pk_f32_fp8((v).y, false);                 \
  a3 += __builtin_amdgcn_cvt_pk_f32_fp8((v).y, true);                  \
  a4 += __builtin_amdgcn_cvt_pk_f32_fp8((v).z, false);                 \
  a5 += __builtin_amdgcn_cvt_pk_f32_fp8((v).z, true);                  \
  a6 += __builtin_amdgcn_cvt_pk_f32_fp8((v).w, false);                 \
  a7 += __builtin_amdgcn_cvt_pk_f32_fp8((v).w, true);

// layer-1: fp8 x rows (64B); 4 lanes x uint4 per row -> 16 rows per wave-load
__global__ __launch_bounds__(256) void gather_mean_64f8(const u8* __restrict__ x8,
                                                        const int* __restrict__ rowptr,
                                                        const int* __restrict__ csr,
                                                        u16* __restrict__ mean, int N) {
  int n = (blockIdx.x * 256 + threadIdx.x) >> 6;
  int lane = threadIdx.x & 63;
  int sub = lane >> 2;      // edge slot 0..15
  int ln = lane & 3;        // 16B chunk of 64B row
  if (n >= N) return;
  int s0 = rowptr[n], s1 = rowptr[n + 1];
  f32x2 a0 = (f32x2)(0.f), a1 = (f32x2)(0.f), a2 = (f32x2)(0.f), a3 = (f32x2)(0.f);
  f32x2 a4 = (f32x2)(0.f), a5 = (f32x2)(0.f), a6 = (f32x2)(0.f), a7 = (f32x2)(0.f);
  int e = s0;
  for (; e + 32 <= s1; e += 32) {
    int i0 = csr[e + sub], i1 = csr[e + 16 + sub];
    uint4 v0 = *(const uint4*)(x8 + (size_t)i0 * 64 + ln * 16);
    uint4 v1 = *(const uint4*)(x8 + (size_t)i1 * 64 + ln * 16);
    F8ACC16(v0); F8ACC16(v1);
  }
  for (; e + 16 <= s1; e += 16) {
    int i0 = csr[e + sub];
    uint4 v0 = *(const uint4*)(x8 + (size_t)i0 * 64 + ln * 16);
    F8ACC16(v0);
  }
  int rem = s1 - e;
  if (sub < rem) {
    int i0 = csr[e + sub];
    uint4 v0 = *(const uint4*)(x8 + (size_t)i0 * 64 + ln * 16);
    F8ACC16(v0);
  }
#pragma unroll
  for (int off = 4; off < 64; off <<= 1) {
    a0.x += __shfl_xor(a0.x, off); a0.y += __shfl_xor(a0.y, off);
    a1.x += __shfl_xor(a1.x, off); a1.y += __shfl_xor(a1.y, off);
    a2.x += __shfl_xor(a2.x, off); a2.y += __shfl_xor(a2.y, off);
    a3.x += __shfl_xor(a3.x, off); a3.y += __shfl_xor(a3.y, off);
    a4.x += __shfl_xor(a4.x, off); a4.y += __shfl_xor(a4.y, off);
    a5.x += __shfl_xor(a5.x, off); a5.y += __shfl_xor(a5.y, off);
    a6.x += __shfl_xor(a6.x, off); a6.y += __shfl_xor(a6.y, off);
    a7.x += __shfl_xor(a7.x, off); a7.y += __shfl_xor(a7.y, off);
  }
  if (sub == 0) {
    int c = s1 - s0;
    float inv = c > 0 ? 1.f / (float)c : 0.f;
    uint4 o0, o1;
    o0.x = (u32)f2b(a0.x * inv) | ((u32)f2b(a0.y * inv) << 16);
    o0.y = (u32)f2b(a1.x * inv) | ((u32)f2b(a1.y * inv) << 16);
    o0.z = (u32)f2b(a2.x * inv) | ((u32)f2b(a2.y * inv) << 16);
    o0.w = (u32)f2b(a3.x * inv) | ((u32)f2b(a3.y * inv) << 16);
    o1.x = (u32)f2b(a4.x * inv) | ((u32)f2b(a4.y * inv) << 16);
    o1.y = (u32)f2b(a5.x * inv) | ((u32)f2b(a5.y * inv) << 16);
    o1.z = (u32)f2b(a6.x * inv) | ((u32)f2b(a6.y * inv) << 16);
    o1.w = (u32)f2b(a7.x * inv) | ((u32)f2b(a7.y * inv) << 16);
    uint4* mp = (uint4*)(mean + (size_t)n * 64 + ln * 16);
    mp[0] = o0; mp[1] = o1;
  }
}

// layer-2: fp8 h1 rows (128B); 8 lanes x uint4 per row -> 8 rows per wave-load
__global__ __launch_bounds__(256) void gather_mean_128f8(const u8* __restrict__ h8,
                                                         const int* __restrict__ rowptr,
                                                         const int* __restrict__ csr,
                                                         u16* __restrict__ mean, int N) {
  int n = (blockIdx.x * 256 + threadIdx.x) >> 6;
  int lane = threadIdx.x & 63;
  int sub = lane >> 3;      // edge slot 0..7
  int ln = lane & 7;        // 16B chunk of 128B row
  if (n >= N) return;
  int s0 = rowptr[n], s1 = rowptr[n + 1];
  f32x2 a0 = (f32x2)(0.f), a1 = (f32x2)(0.f), a2 = (f32x2)(0.f), a3 = (f32x2)(0.f);
  f32x2 a4 = (f32x2)(0.f), a5 = (f32x2)(0.f), a6 = (f32x2)(0.f), a7 = (f32x2)(0.f);
  int e = s0;
  for (; e + 16 <= s1; e += 16) {
    int i0 = csr[e + sub], i1 = csr[e + 8 + sub];
    uint4 v0 = *(const uint4*)(h8 + (size_t)i0 * 128 + ln * 16);
    uint4 v1 = *(const uint4*)(h8 + (size_t)i1 * 128 + ln * 16);
    F8ACC16(v0); F8ACC16(v1);
  }
  for (; e + 8 <= s1; e += 8) {
    int i0 = csr[e + sub];
    uint4 v0 = *(const uint4*)(h8 + (size_t)i0 * 128 + ln * 16);
    F8ACC16(v0);
  }
  int rem = s1 - e;
  if (sub < rem) {
    int i0 = csr[e + sub];
    uint4 v0 = *(const uint4*)(h8 + (size_t)i0 * 128 + ln * 16);
    F8ACC16(v0);
  }
#pragma unroll
  for (int off = 8; off < 64; off <<= 1) {
    a0.x += __shfl_xor(a0.x, off); a0.y += __shfl_xor(a0.y, off);
    a1.x += __shfl_xor(a1.x, off); a1.y += __shfl_xor(a1.y, off);
    a2.x += __shfl_xor(a2.x, off); a2.y += __shfl_xor(a2.y, off);
    a3.x += __shfl_xor(a3.x, off); a3.y += __shfl_xor(a3.y, off);
    a4.x += __shfl_xor(a4.x, off); a4.y += __shfl_xor(a4.y, off);
    a5.x += __shfl_xor(a5.x, off); a5.y += __shfl_xor(a5.y, off);
    a6.x += __shfl_xor(a6.x, off); a6.y += __shfl_xor(a6.y, off);
    a7.x += __shfl_xor(a7.x, off); a7.y += __shfl_xor(a7.y, off);
  }
  if (sub == 0) {
    int c = s1 - s0;
    float inv = c > 0 ? 1.f / (float)c : 0.f;
    uint4 o0, o1;
    o0.x = (u32)f2b(a0.x * inv) | ((u32)f2b(a0.y * inv) << 16);
    o0.y = (u32)f2b(a1.x * inv) | ((u32)f2b(a1.y * inv) << 16);
    o0.z = (u32)f2b(a2.x * inv) | ((u32)f2b(a2.y * inv) << 16);
    o0.w = (u32)f2b(a3.x * inv) | ((u32)f2b(a3.y * inv) << 16);
    o1.x = (u32)f2b(a4.x * inv) | ((u32)f2b(a4.y * inv) << 16);
    o1.y = (u32)f2b(a5.x * inv) | ((u32)f2b(a5.y * inv) << 16);
    o1.z = (u32)f2b(a6.x * inv) | ((u32)f2b(a6.y * inv) << 16);
    o1.w = (u32)f2b(a7.x * inv) | ((u32)f2b(a7.y * inv) << 16);
    uint4* mp = (uint4*)(mean + (size_t)n * 128 + ln * 16);
    mp[0] = o0; mp[1] = o1;
  }
}

// ---------------- MFMA GEMM ----------------
// !FINAL: writes h1 bf16 + fp8 side copy. FINAL: fuses p,q projection.
template<int K2, bool FINAL>
__global__ __launch_bounds__(512) void mfma_gemm(
    const u16* __restrict__ meanb, const u16* __restrict__ prevb,
    const u16* __restrict__ wt,    // [128][K2] bf16 (pre-transposed)
    const float* __restrict__ bias,
    u16* __restrict__ hout, u8* __restrict__ hout8,
    const float* __restrict__ W3l, const float* __restrict__ W3r,
    float* __restrict__ outp, float* __restrict__ outq, int N) {
  constexpr int KH = K2 / 2;
  constexpr int NC = K2 / 8;
  __shared__ __align__(16) u16 Albs[128 * K2];
  __shared__ __align__(16) u16 Wlds[128 * K2];

  const int t = threadIdx.x;
  const int tile = blockIdx.x * 128;

  for (int i = t; i < 128 * NC; i += 512) {
    int j = i / NC, c = i - j * NC;
    uint4 v = *(const uint4*)(wt + (size_t)j * K2 + c * 8);
    *(uint4*)(Wlds + j * K2 + ((c ^ (j & 7)) << 3)) = v;
  }
  for (int i = t; i < 128 * NC; i += 512) {
    int r = i / NC, c = i - r * NC;
    int node = tile + r;
    uint4 v; v.x = 0; v.y = 0; v.z = 0; v.w = 0;
    if (node < N) {
      int k0 = c * 8;
      v = (k0 < KH) ? *(const uint4*)(meanb + (size_t)node * KH + k0)
                    : *(const uint4*)(prevb + (size_t)node * KH + (k0 - KH));
    }
    *(uint4*)(Albs + r * K2 + ((c ^ (r & 7)) << 3)) = v;
  }
  __syncthreads();

  const int lane = t & 63;
  const int wid = t >> 6;
  const int wm = wid >> 1, wn = wid & 1;
  const int er = lane & 15;
  const int kg = lane >> 4;

  f32x4 acc[2][4];
#pragma unroll
  for (int mi = 0; mi < 2; ++mi)
#pragma unroll
    for (int ni = 0; ni < 4; ++ni) acc[mi][ni] = (f32x4)(0.f);

#pragma unroll
  for (int ks = 0; ks < K2 / 32; ++ks) {
    int cidx = ks * 4 + kg;
    s16x8 a[2], b[4];
#pragma unroll
    for (int mi = 0; mi < 2; ++mi) {
      int row = wm * 32 + mi * 16 + er;
      a[mi] = *(const s16x8*)(Albs + row * K2 + ((cidx ^ (row & 7)) << 3));
    }
#pragma unroll
    for (int ni = 0; ni < 4; ++ni) {
      int col = wn * 64 + ni * 16 + er;
      b[ni] = *(const s16x8*)(Wlds + col * K2 + ((cidx ^ (col & 7)) << 3));
    }
#pragma unroll
    for (int mi = 0; mi < 2; ++mi)
#pragma unroll
      for (int ni = 0; ni < 4; ++ni)
        acc[mi][ni] = __builtin_amdgcn_mfma_f32_16x16x32_bf16(a[mi], b[ni], acc[mi][ni], 0, 0, 0);
  }

  if constexpr (!FINAL) {
#pragma unroll
    for (int mi = 0; mi < 2; ++mi) {
#pragma unroll
      for (int ni = 0; ni < 4; ++ni) {
        int col = wn * 64 + ni * 16 + er;
        float bv = bias[col];
#pragma unroll
        for (int r = 0; r < 4; ++r) {
          int node = tile + wm * 32 + mi * 16 + kg * 4 + r;
          if (node < N) {
            float v = acc[mi][ni][r] + bv;
            v = v > 0.f ? v : 0.f;
            hout[(size_t)node * 128 + col] = f2b(v);
            u32 pk = __builtin_amdgcn_cvt_pk_fp8_f32(v, v, 0, false);
            hout8[(size_t)node * 128 + col] = (u8)pk;
          }
        }
      }
    }
  } else {
    __shared__ float p_lds[128][2], q_lds[128][2];
    float wl[4], wr[4], bv[4];
#pragma unroll
    for (int ni = 0; ni < 4; ++ni) {
      int col = wn * 64 + ni * 16 + er;
      wl[ni] = W3l[col]; wr[ni] = W3r[col]; bv[ni] = bias[col];
    }
#pragma unroll
    for (int mi = 0; mi < 2; ++mi) {
#pragma unroll
      for (int r = 0; r < 4; ++r) {
        float pv = 0.f, qv = 0.f;
#pragma unroll
        for (int ni = 0; ni < 4; ++ni) {
          float v = acc[mi][ni][r] + bv[ni];
          v = v > 0.f ? v : 0.f;
          pv = fmaf(v, wl[ni], pv);
          qv = fmaf(v, wr[ni], qv);
        }
#pragma unroll
        for (int off = 1; off < 16; off <<= 1) {
          pv += __shfl_xor(pv, off);
          qv += __shfl_xor(qv, off);
        }
        if (er == 0) {
          int nl = wm * 32 + mi * 16 + kg * 4 + r;
          p_lds[nl][wn] = pv;
          q_lds[nl][wn] = qv;
        }
      }
    }
    __syncthreads();
    if (t < 128) {
      int node = tile + t;
      if (node < N) {
        outp[node] = p_lds[t][0] + p_lds[t][1];
        outq[node] = q_lds[t][0] + q_lds[t][1];
      }
    }
  }
}

// ---------------- layer 3 fused: h3 = mean_e(p) + q + b3 ; out_scalar ----------------
__global__ __launch_bounds__(256) void gather3_fused(const float* __restrict__ p,
                                                     const int* __restrict__ rowptr,
                                                     const int* __restrict__ csr,
                                                     const float* __restrict__ q,
                                                     const float* __restrict__ b3,
                                                     float* __restrict__ h3,
                                                     float* __restrict__ out_scalar, int N) {
  int n = blockIdx.x * 256 + threadIdx.x;
  if (n >= N) return;
  int s0 = rowptr[n], s1 = rowptr[n + 1];
  float a = 0.f;
  for (int e = s0; e < s1; ++e) a += p[csr[e]];
  int c = s1 - s0;
  float inv = c > 0 ? 1.f / (float)c : 0.f;
  float v = a * inv + q[n] + b3[0];
  h3[n] = v;
  out_scalar[n] = v;
}

// ---------------- layer 4 fused: mean_e(h3) -> logits -> log_softmax ----------------
__global__ __launch_bounds__(256) void gather4_fused(const float* __restrict__ h3,
                                                     const int* __restrict__ rowptr,
                                                     const int* __restrict__ csr,
                                                     const float* __restrict__ W4l,
                                                     const float* __restrict__ W4r,
                                                     const float* __restrict__ b4,
                                                     float* __restrict__ out, int N) {
  int n = blockIdx.x * 256 + threadIdx.x;
  if (n >= N) return;
  int s0 = rowptr[n], s1 = rowptr[n + 1];
  float a = 0.f;
  for (int e = s0; e < s1; ++e) a += h3[csr[e]];
  int c = s1 - s0;
  float inv = c > 0 ? 1.f / (float)c : 0.f;
  float m = a * inv;
  float hv = h3[n];
  float logits[8];
  float mx = -1e30f;
#pragma unroll
  for (int jj = 0; jj < 8; ++jj) {
    float v = m * W4l[jj] + hv * W4r[jj] + b4[jj];
    logits[jj] = v;
    mx = v > mx ? v : mx;
  }
  float s = 0.f;
#pragma unroll
  for (int jj = 0; jj < 8; ++jj) s += expf(logits[jj] - mx);
  float lse = mx + logf(s);
  float4 o0, o1;
  o0.x = logits[0] - lse; o0.y = logits[1] - lse; o0.z = logits[2] - lse; o0.w = logits[3] - lse;
  o1.x = logits[4] - lse; o1.y = logits[5] - lse; o1.z = logits[6] - lse; o1.w = logits[7] - lse;
  float4* o4 = (float4*)(out + (size_t)n * 8);
  o4[0] = o0; o4[1] = o1;
}

extern "C" void kernel_launch(void* const* d_in, const int* in_sizes, int n_in,
                              void* d_out, int out_size, void* d_ws, size_t ws_size,
                              hipStream_t stream) {
  const float* x   = (const float*)d_in[0];
  const int*   ei  = (const int*)d_in[1];
  const float* W1l = (const float*)d_in[2];
  const float* W1r = (const float*)d_in[3];
  const float* b1  = (const float*)d_in[4];
  const float* W2l = (const float*)d_in[5];
  const float* W2r = (const float*)d_in[6];
  const float* b2  = (const float*)d_in[7];
  const float* W3l = (const float*)d_in[8];
  const float* W3r = (const float*)d_in[9];
  const float* b3  = (const float*)d_in[10];
  const float* W4l = (const float*)d_in[11];
  const float* W4r = (const float*)d_in[12];
  const float* b4  = (const float*)d_in[13];

  const int N = in_sizes[0] / 64;   // 100000
  const int E = in_sizes[1] / 2;    // 1600000
  const size_t Ns = (size_t)N;
  const int B = (N + 127) >> 7;     // 782 buckets
  const int NBLK = (E + 8191) / 8192;  // 196

  // ---- workspace layout ----
  u16* ub      = (u16*)d_ws;
  u16* xb      = ub;                 // 64N
  u16* mean0b  = ub + 64 * Ns;       // 64N
  u16* h1b     = ub + 128 * Ns;      // 128N
  u16* mean1b  = ub + 256 * Ns;      // 128N
  u16* wt1     = ub + 384 * Ns;      // 16384
  u16* wt2     = wt1 + 16384;        // 32768
  u8*  h8      = (u8*)(wt2 + 32768); // 128N bytes (fp8 h1)
  u8*  x8      = h8 + 128 * Ns;      // 64N bytes (fp8 x)
  float* fb    = (float*)(x8 + 64 * Ns);
  float* p     = fb;                 // N
  float* q     = fb + Ns;            // N
  float* h3    = fb + 2 * Ns;        // N
  int* ib      = (int*)(fb + 3 * Ns);
  int* rowptr       = ib;                      // N+1
  int* gcur         = ib + (N + 1);            // 1024
  int* bucket_base  = gcur + 1024;             // 1025
  int* csr          = bucket_base + 1025;      // E
  u32* staging      = (u32*)(csr + E);         // 1024*BCAP

  float* out_rock   = (float*)d_out;            // N x 8
  float* out_scalar = (float*)d_out + 8 * Ns;   // N

  const int GG = (N + 127) / 128;
  const int total4 = N * 16;

  // ---- CSR build ----
  hipMemsetAsync(gcur, 0, 1024 * sizeof(int), stream);
  bucketize<<<NBLK, 512, 0, stream>>>(ei, gcur, staging, E, B);
  scan_tiny<<<1, 512, 0, stream>>>(gcur, bucket_base, rowptr, N, E);
  place<<<B, 256, 0, stream>>>(staging, bucket_base, rowptr, csr, N);

  // ---- conversions ----
  cvt_all<<<(total4 + 49152 + 255) / 256, 256, 0, stream>>>(
      x, xb, (u32*)x8, total4, W1l, W1r, W2l, W2r, wt1, wt2);

  // ---- layer 1 ----
  gather_mean_64f8<<<(N + 3) / 4, 256, 0, stream>>>(x8, rowptr, csr, mean0b, N);
  mfma_gemm<128, false><<<GG, 512, 0, stream>>>(
      mean0b, xb, wt1, b1, h1b, h8, nullptr, nullptr, nullptr, nullptr, N);

  // ---- layer 2 (+ fused p,q) ----
  gather_mean_128f8<<<(N + 3) / 4, 256, 0, stream>>>(h8, rowptr, csr, mean1b, N);
  mfma_gemm<256, true><<<GG, 512, 0, stream>>>(
      mean1b, h1b, wt2, b2, nullptr, nullptr, W3l, W3r, p, q, N);

  // ---- layer 3 (scalar) ----
  gather3_fused<<<(N + 255) / 256, 256, 0, stream>>>(p, rowptr, csr, q, b3, h3, out_scalar, N);

  // ---- layer 4 (scalar in, 8 out) ----
  gather4_fused<<<(N + 255) / 256, 256, 0, stream>>>(h3, rowptr, csr, W4l, W4r, b4, out_rock, N);
}

// Round 14
// 232.392 us; speedup vs baseline: 1.1339x; 1.1339x over previous
//
#include <hip/hip_runtime.h>
#include <hip/hip_bf16.h>
#include <math.h>

// GraphSAGE: 4 layers on N=100000 nodes, E=1600000 edges.
// Round 14: fix gather_mean_64f8 regression — 8 lanes/row x uint2 (8 rows per
// wave-instr, the measured-fast config), instead of 4 lanes/row x uint4
// (16 rows/instr, which serialized the TA pipe at 73us). Rest = round 13.

typedef unsigned char u8;
typedef unsigned short u16;
typedef unsigned int u32;
typedef __attribute__((ext_vector_type(2))) float f32x2;
typedef __attribute__((ext_vector_type(4))) float f32x4;
typedef __attribute__((ext_vector_type(8))) short s16x8;

#define BCAP 4096  // staging capacity per bucket (mean 2048, +45 sigma)

__device__ __forceinline__ float b2f(u16 u) {
  union { float f; u32 i; } v; v.i = ((u32)u) << 16; return v.f;
}
__device__ __forceinline__ u16 f2b(float f) {
  union { float f; u32 u; } v; v.f = f;
  u32 r = v.u + 0x7fffu + ((v.u >> 16) & 1u);   // RTN-even
  return (u16)(r >> 16);
}

// ---------------- CSR build ----------------
__global__ __launch_bounds__(512) void bucketize(const int* __restrict__ ei,
                                                 int* __restrict__ gcur,
                                                 u32* __restrict__ staging,
                                                 int E, int B) {
  __shared__ u32 vals[8192];
  __shared__ u16 bkt[8192];
  __shared__ int hist[1024], ofs[1024], curx[1024], gbase[1024];
  __shared__ int wsum[512];

  const int t = threadIdx.x;
  const int base = blockIdx.x * 8192;
  const int cnt = min(8192, E - base);

  for (int b = t; b < 1024; b += 512) hist[b] = 0;
  __syncthreads();

  for (int k = t; k < cnt; k += 512) {
    int d = ei[E + base + k];
    atomicAdd(&hist[d >> 7], 1);
  }
  __syncthreads();

  int a0 = hist[2 * t], a1 = hist[2 * t + 1];
  int s = a0 + a1;
  wsum[t] = s;
  __syncthreads();
  for (int off = 1; off < 512; off <<= 1) {
    int add = (t >= off) ? wsum[t - off] : 0;
    __syncthreads();
    wsum[t] += add;
    __syncthreads();
  }
  int excl = wsum[t] - s;
  ofs[2 * t] = excl;
  ofs[2 * t + 1] = excl + a0;
  __syncthreads();

  for (int b = t; b < B; b += 512) {
    int c = hist[b];
    gbase[b] = c ? atomicAdd(&gcur[b], c) : 0;
    curx[b] = ofs[b];
  }
  __syncthreads();

  for (int k = t; k < cnt; k += 512) {
    int sv = ei[base + k];
    int d = ei[E + base + k];
    int b = d >> 7;
    u32 val = (u32)sv | ((u32)(d & 127) << 17);
    int lpos = atomicAdd(&curx[b], 1);
    vals[lpos] = val;
    bkt[lpos] = (u16)b;
  }
  __syncthreads();

  for (int i = t; i < cnt; i += 512) {
    int b = bkt[i];
    staging[(size_t)b * BCAP + gbase[b] + (i - ofs[b])] = vals[i];
  }
}

__global__ __launch_bounds__(512) void scan_tiny(const int* __restrict__ gcur,
                                                 int* __restrict__ bucket_base,
                                                 int* __restrict__ rowptr,
                                                 int N, int E) {
  __shared__ int wsum[512];
  const int t = threadIdx.x;
  int c0 = gcur[2 * t];
  int c1 = gcur[2 * t + 1];
  int s = c0 + c1;
  wsum[t] = s;
  __syncthreads();
  for (int off = 1; off < 512; off <<= 1) {
    int add = (t >= off) ? wsum[t - off] : 0;
    __syncthreads();
    wsum[t] += add;
    __syncthreads();
  }
  int excl = wsum[t] - s;
  bucket_base[2 * t] = excl;
  bucket_base[2 * t + 1] = excl + c0;
  if (t == 511) bucket_base[1024] = wsum[511];
  if (t == 0) rowptr[N] = E;
}

__global__ __launch_bounds__(256) void place(const u32* __restrict__ staging,
                                             const int* __restrict__ bucket_base,
                                             int* __restrict__ rowptr,
                                             int* __restrict__ csr, int N) {
  __shared__ int cnt[128], excl[128], cur[128], sc[128];
  const int t = threadIdx.x;
  const int node0 = blockIdx.x << 7;
  const int nn = min(128, N - node0);
  if (t < 128) { cnt[t] = 0; cur[t] = 0; }
  __syncthreads();
  const int rstart = bucket_base[blockIdx.x];
  const int ec = bucket_base[blockIdx.x + 1] - rstart;
  const u32* slice = staging + (size_t)blockIdx.x * BCAP;
  for (int i = t; i < ec; i += 256)
    atomicAdd(&cnt[slice[i] >> 17], 1);
  __syncthreads();
  if (t < 128) sc[t] = cnt[t];
  __syncthreads();
  for (int off = 1; off < 128; off <<= 1) {
    int add = (t < 128 && t >= off) ? sc[t - off] : 0;
    __syncthreads();
    if (t < 128) sc[t] += add;
    __syncthreads();
  }
  if (t < 128) excl[t] = sc[t] - cnt[t];
  if (t < nn) rowptr[node0 + t] = rstart + excl[t];
  __syncthreads();
  for (int i = t; i < ec; i += 256) {
    u32 v = slice[i];
    int nl = v >> 17;
    int src = v & 0x1FFFF;
    int tk = atomicAdd(&cur[nl], 1);
    csr[rstart + excl[nl] + tk] = src;
  }
}

// ---------------- conversions (fused) ----------------
__global__ __launch_bounds__(256) void cvt_all(const float* __restrict__ x,
                                               u16* __restrict__ xb,
                                               u32* __restrict__ x8,  // fp8 x table
                                               int total4,
                                               const float* __restrict__ W1l,
                                               const float* __restrict__ W1r,
                                               const float* __restrict__ W2l,
                                               const float* __restrict__ W2r,
                                               u16* __restrict__ wt1,
                                               u16* __restrict__ wt2) {
  int i = blockIdx.x * 256 + threadIdx.x;
  if (i < total4) {
    float4 v = *(const float4*)(x + (size_t)i * 4);
    u32 lo = (u32)f2b(v.x) | ((u32)f2b(v.y) << 16);
    u32 hi = (u32)f2b(v.z) | ((u32)f2b(v.w) << 16);
    uint2 o; o.x = lo; o.y = hi;
    *(uint2*)(xb + (size_t)i * 4) = o;
    u32 pk = __builtin_amdgcn_cvt_pk_fp8_f32(v.x, v.y, 0, false);
    pk = __builtin_amdgcn_cvt_pk_fp8_f32(v.z, v.w, pk, true);
    x8[i] = pk;
    return;
  }
  int j = i - total4;
  if (j < 16384) {                 // Wt1: 128 x 128
    int jj = j >> 7, k = j & 127;
    float v = (k < 64) ? W1l[k * 128 + jj] : W1r[(k - 64) * 128 + jj];
    wt1[jj * 128 + k] = f2b(v);
  } else if (j < 16384 + 32768) {  // Wt2: 128 x 256
    int i2 = j - 16384;
    int jj = i2 >> 8, k = i2 & 255;
    float v = (k < 128) ? W2l[k * 128 + jj] : W2r[(k - 128) * 128 + jj];
    wt2[jj * 256 + k] = f2b(v);
  }
}

// ---------------- fp8 gather means ----------------
// accumulate 8 fp8 (uint2) into 4 f32x2
#define F8ACC8(v)                                                      \
  a0 += __builtin_amdgcn_cvt_pk_f32_fp8((v).x, false);                 \
  a1 += __builtin_amdgcn_cvt_pk_f32_fp8((v).x, true);                  \
  a2 += __builtin_amdgcn_cvt_pk_f32_fp8((v).y, false);                 \
  a3 += __builtin_amdgcn_cvt_pk_f32_fp8((v).y, true);

// accumulate 16 fp8 (uint4) into 8 f32x2
#define F8ACC16(v)                                                     \
  a0 += __builtin_amdgcn_cvt_pk_f32_fp8((v).x, false);                 \
  a1 += __builtin_amdgcn_cvt_pk_f32_fp8((v).x, true);                  \
  a2 += __builtin_amdgcn_cvt_pk_f32_fp8((v).y, false);                 \
  a3 += __builtin_amdgcn_cvt_pk_f32_fp8((v).y, true);                  \
  a4 += __builtin_amdgcn_cvt_pk_f32_fp8((v).z, false);                 \
  a5 += __builtin_amdgcn_cvt_pk_f32_fp8((v).z, true);                  \
  a6 += __builtin_amdgcn_cvt_pk_f32_fp8((v).w, false);                 \
  a7 += __builtin_amdgcn_cvt_pk_f32_fp8((v).w, true);

// layer-1: fp8 x rows (64B); 8 lanes x uint2 per row -> 8 rows per wave-load
__global__ __launch_bounds__(256) void gather_mean_64f8(const u8* __restrict__ x8,
                                                        const int* __restrict__ rowptr,
                                                        const int* __restrict__ csr,
                                                        u16* __restrict__ mean, int N) {
  int n = (blockIdx.x * 256 + threadIdx.x) >> 6;
  int lane = threadIdx.x & 63;
  int sub = lane >> 3;      // edge slot 0..7
  int ln = lane & 7;        // 8B chunk of 64B row (8 dims)
  if (n >= N) return;
  int s0 = rowptr[n], s1 = rowptr[n + 1];
  f32x2 a0 = (f32x2)(0.f), a1 = (f32x2)(0.f), a2 = (f32x2)(0.f), a3 = (f32x2)(0.f);
  int e = s0;
  for (; e + 16 <= s1; e += 16) {
    int i0 = csr[e + sub], i1 = csr[e + 8 + sub];
    uint2 v0 = *(const uint2*)(x8 + (size_t)i0 * 64 + ln * 8);
    uint2 v1 = *(const uint2*)(x8 + (size_t)i1 * 64 + ln * 8);
    F8ACC8(v0); F8ACC8(v1);
  }
  for (; e + 8 <= s1; e += 8) {
    int i0 = csr[e + sub];
    uint2 v0 = *(const uint2*)(x8 + (size_t)i0 * 64 + ln * 8);
    F8ACC8(v0);
  }
  int rem = s1 - e;
  if (sub < rem) {
    int i0 = csr[e + sub];
    uint2 v0 = *(const uint2*)(x8 + (size_t)i0 * 64 + ln * 8);
    F8ACC8(v0);
  }
#pragma unroll
  for (int off = 8; off < 64; off <<= 1) {
    a0.x += __shfl_xor(a0.x, off); a0.y += __shfl_xor(a0.y, off);
    a1.x += __shfl_xor(a1.x, off); a1.y += __shfl_xor(a1.y, off);
    a2.x += __shfl_xor(a2.x, off); a2.y += __shfl_xor(a2.y, off);
    a3.x += __shfl_xor(a3.x, off); a3.y += __shfl_xor(a3.y, off);
  }
  if (sub == 0) {
    int c = s1 - s0;
    float inv = c > 0 ? 1.f / (float)c : 0.f;
    uint4 o;
    o.x = (u32)f2b(a0.x * inv) | ((u32)f2b(a0.y * inv) << 16);
    o.y = (u32)f2b(a1.x * inv) | ((u32)f2b(a1.y * inv) << 16);
    o.z = (u32)f2b(a2.x * inv) | ((u32)f2b(a2.y * inv) << 16);
    o.w = (u32)f2b(a3.x * inv) | ((u32)f2b(a3.y * inv) << 16);
    *(uint4*)(mean + (size_t)n * 64 + ln * 8) = o;
  }
}

// layer-2: fp8 h1 rows (128B); 8 lanes x uint4 per row -> 8 rows per wave-load
__global__ __launch_bounds__(256) void gather_mean_128f8(const u8* __restrict__ h8,
                                                         const int* __restrict__ rowptr,
                                                         const int* __restrict__ csr,
                                                         u16* __restrict__ mean, int N) {
  int n = (blockIdx.x * 256 + threadIdx.x) >> 6;
  int lane = threadIdx.x & 63;
  int sub = lane >> 3;      // edge slot 0..7
  int ln = lane & 7;        // 16B chunk of 128B row
  if (n >= N) return;
  int s0 = rowptr[n], s1 = rowptr[n + 1];
  f32x2 a0 = (f32x2)(0.f), a1 = (f32x2)(0.f), a2 = (f32x2)(0.f), a3 = (f32x2)(0.f);
  f32x2 a4 = (f32x2)(0.f), a5 = (f32x2)(0.f), a6 = (f32x2)(0.f), a7 = (f32x2)(0.f);
  int e = s0;
  for (; e + 16 <= s1; e += 16) {
    int i0 = csr[e + sub], i1 = csr[e + 8 + sub];
    uint4 v0 = *(const uint4*)(h8 + (size_t)i0 * 128 + ln * 16);
    uint4 v1 = *(const uint4*)(h8 + (size_t)i1 * 128 + ln * 16);
    F8ACC16(v0); F8ACC16(v1);
  }
  for (; e + 8 <= s1; e += 8) {
    int i0 = csr[e + sub];
    uint4 v0 = *(const uint4*)(h8 + (size_t)i0 * 128 + ln * 16);
    F8ACC16(v0);
  }
  int rem = s1 - e;
  if (sub < rem) {
    int i0 = csr[e + sub];
    uint4 v0 = *(const uint4*)(h8 + (size_t)i0 * 128 + ln * 16);
    F8ACC16(v0);
  }
#pragma unroll
  for (int off = 8; off < 64; off <<= 1) {
    a0.x += __shfl_xor(a0.x, off); a0.y += __shfl_xor(a0.y, off);
    a1.x += __shfl_xor(a1.x, off); a1.y += __shfl_xor(a1.y, off);
    a2.x += __shfl_xor(a2.x, off); a2.y += __shfl_xor(a2.y, off);
    a3.x += __shfl_xor(a3.x, off); a3.y += __shfl_xor(a3.y, off);
    a4.x += __shfl_xor(a4.x, off); a4.y += __shfl_xor(a4.y, off);
    a5.x += __shfl_xor(a5.x, off); a5.y += __shfl_xor(a5.y, off);
    a6.x += __shfl_xor(a6.x, off); a6.y += __shfl_xor(a6.y, off);
    a7.x += __shfl_xor(a7.x, off); a7.y += __shfl_xor(a7.y, off);
  }
  if (sub == 0) {
    int c = s1 - s0;
    float inv = c > 0 ? 1.f / (float)c : 0.f;
    uint4 o0, o1;
    o0.x = (u32)f2b(a0.x * inv) | ((u32)f2b(a0.y * inv) << 16);
    o0.y = (u32)f2b(a1.x * inv) | ((u32)f2b(a1.y * inv) << 16);
    o0.z = (u32)f2b(a2.x * inv) | ((u32)f2b(a2.y * inv) << 16);
    o0.w = (u32)f2b(a3.x * inv) | ((u32)f2b(a3.y * inv) << 16);
    o1.x = (u32)f2b(a4.x * inv) | ((u32)f2b(a4.y * inv) << 16);
    o1.y = (u32)f2b(a5.x * inv) | ((u32)f2b(a5.y * inv) << 16);
    o1.z = (u32)f2b(a6.x * inv) | ((u32)f2b(a6.y * inv) << 16);
    o1.w = (u32)f2b(a7.x * inv) | ((u32)f2b(a7.y * inv) << 16);
    uint4* mp = (uint4*)(mean + (size_t)n * 128 + ln * 16);
    mp[0] = o0; mp[1] = o1;
  }
}

// ---------------- MFMA GEMM ----------------
// !FINAL: writes h1 bf16 + fp8 side copy. FINAL: fuses p,q projection.
template<int K2, bool FINAL>
__global__ __launch_bounds__(512) void mfma_gemm(
    const u16* __restrict__ meanb, const u16* __restrict__ prevb,
    const u16* __restrict__ wt,    // [128][K2] bf16 (pre-transposed)
    const float* __restrict__ bias,
    u16* __restrict__ hout, u8* __restrict__ hout8,
    const float* __restrict__ W3l, const float* __restrict__ W3r,
    float* __restrict__ outp, float* __restrict__ outq, int N) {
  constexpr int KH = K2 / 2;
  constexpr int NC = K2 / 8;
  __shared__ __align__(16) u16 Albs[128 * K2];
  __shared__ __align__(16) u16 Wlds[128 * K2];

  const int t = threadIdx.x;
  const int tile = blockIdx.x * 128;

  for (int i = t; i < 128 * NC; i += 512) {
    int j = i / NC, c = i - j * NC;
    uint4 v = *(const uint4*)(wt + (size_t)j * K2 + c * 8);
    *(uint4*)(Wlds + j * K2 + ((c ^ (j & 7)) << 3)) = v;
  }
  for (int i = t; i < 128 * NC; i += 512) {
    int r = i / NC, c = i - r * NC;
    int node = tile + r;
    uint4 v; v.x = 0; v.y = 0; v.z = 0; v.w = 0;
    if (node < N) {
      int k0 = c * 8;
      v = (k0 < KH) ? *(const uint4*)(meanb + (size_t)node * KH + k0)
                    : *(const uint4*)(prevb + (size_t)node * KH + (k0 - KH));
    }
    *(uint4*)(Albs + r * K2 + ((c ^ (r & 7)) << 3)) = v;
  }
  __syncthreads();

  const int lane = t & 63;
  const int wid = t >> 6;
  const int wm = wid >> 1, wn = wid & 1;
  const int er = lane & 15;
  const int kg = lane >> 4;

  f32x4 acc[2][4];
#pragma unroll
  for (int mi = 0; mi < 2; ++mi)
#pragma unroll
    for (int ni = 0; ni < 4; ++ni) acc[mi][ni] = (f32x4)(0.f);

#pragma unroll
  for (int ks = 0; ks < K2 / 32; ++ks) {
    int cidx = ks * 4 + kg;
    s16x8 a[2], b[4];
#pragma unroll
    for (int mi = 0; mi < 2; ++mi) {
      int row = wm * 32 + mi * 16 + er;
      a[mi] = *(const s16x8*)(Albs + row * K2 + ((cidx ^ (row & 7)) << 3));
    }
#pragma unroll
    for (int ni = 0; ni < 4; ++ni) {
      int col = wn * 64 + ni * 16 + er;
      b[ni] = *(const s16x8*)(Wlds + col * K2 + ((cidx ^ (col & 7)) << 3));
    }
#pragma unroll
    for (int mi = 0; mi < 2; ++mi)
#pragma unroll
      for (int ni = 0; ni < 4; ++ni)
        acc[mi][ni] = __builtin_amdgcn_mfma_f32_16x16x32_bf16(a[mi], b[ni], acc[mi][ni], 0, 0, 0);
  }

  if constexpr (!FINAL) {
#pragma unroll
    for (int mi = 0; mi < 2; ++mi) {
#pragma unroll
      for (int ni = 0; ni < 4; ++ni) {
        int col = wn * 64 + ni * 16 + er;
        float bv = bias[col];
#pragma unroll
        for (int r = 0; r < 4; ++r) {
          int node = tile + wm * 32 + mi * 16 + kg * 4 + r;
          if (node < N) {
            float v = acc[mi][ni][r] + bv;
            v = v > 0.f ? v : 0.f;
            hout[(size_t)node * 128 + col] = f2b(v);
            u32 pk = __builtin_amdgcn_cvt_pk_fp8_f32(v, v, 0, false);
            hout8[(size_t)node * 128 + col] = (u8)pk;
          }
        }
      }
    }
  } else {
    __shared__ float p_lds[128][2], q_lds[128][2];
    float wl[4], wr[4], bv[4];
#pragma unroll
    for (int ni = 0; ni < 4; ++ni) {
      int col = wn * 64 + ni * 16 + er;
      wl[ni] = W3l[col]; wr[ni] = W3r[col]; bv[ni] = bias[col];
    }
#pragma unroll
    for (int mi = 0; mi < 2; ++mi) {
#pragma unroll
      for (int r = 0; r < 4; ++r) {
        float pv = 0.f, qv = 0.f;
#pragma unroll
        for (int ni = 0; ni < 4; ++ni) {
          float v = acc[mi][ni][r] + bv[ni];
          v = v > 0.f ? v : 0.f;
          pv = fmaf(v, wl[ni], pv);
          qv = fmaf(v, wr[ni], qv);
        }
#pragma unroll
        for (int off = 1; off < 16; off <<= 1) {
          pv += __shfl_xor(pv, off);
          qv += __shfl_xor(qv, off);
        }
        if (er == 0) {
          int nl = wm * 32 + mi * 16 + kg * 4 + r;
          p_lds[nl][wn] = pv;
          q_lds[nl][wn] = qv;
        }
      }
    }
    __syncthreads();
    if (t < 128) {
      int node = tile + t;
      if (node < N) {
        outp[node] = p_lds[t][0] + p_lds[t][1];
        outq[node] = q_lds[t][0] + q_lds[t][1];
      }
    }
  }
}

// ---------------- layer 3 fused: h3 = mean_e(p) + q + b3 ; out_scalar ----------------
__global__ __launch_bounds__(256) void gather3_fused(const float* __restrict__ p,
                                                     const int* __restrict__ rowptr,
                                                     const int* __restrict__ csr,
                                                     const float* __restrict__ q,
                                                     const float* __restrict__ b3,
                                                     float* __restrict__ h3,
                                                     float* __restrict__ out_scalar, int N) {
  int n = blockIdx.x * 256 + threadIdx.x;
  if (n >= N) return;
  int s0 = rowptr[n], s1 = rowptr[n + 1];
  float a = 0.f;
  for (int e = s0; e < s1; ++e) a += p[csr[e]];
  int c = s1 - s0;
  float inv = c > 0 ? 1.f / (float)c : 0.f;
  float v = a * inv + q[n] + b3[0];
  h3[n] = v;
  out_scalar[n] = v;
}

// ---------------- layer 4 fused: mean_e(h3) -> logits -> log_softmax ----------------
__global__ __launch_bounds__(256) void gather4_fused(const float* __restrict__ h3,
                                                     const int* __restrict__ rowptr,
                                                     const int* __restrict__ csr,
                                                     const float* __restrict__ W4l,
                                                     const float* __restrict__ W4r,
                                                     const float* __restrict__ b4,
                                                     float* __restrict__ out, int N) {
  int n = blockIdx.x * 256 + threadIdx.x;
  if (n >= N) return;
  int s0 = rowptr[n], s1 = rowptr[n + 1];
  float a = 0.f;
  for (int e = s0; e < s1; ++e) a += h3[csr[e]];
  int c = s1 - s0;
  float inv = c > 0 ? 1.f / (float)c : 0.f;
  float m = a * inv;
  float hv = h3[n];
  float logits[8];
  float mx = -1e30f;
#pragma unroll
  for (int jj = 0; jj < 8; ++jj) {
    float v = m * W4l[jj] + hv * W4r[jj] + b4[jj];
    logits[jj] = v;
    mx = v > mx ? v : mx;
  }
  float s = 0.f;
#pragma unroll
  for (int jj = 0; jj < 8; ++jj) s += expf(logits[jj] - mx);
  float lse = mx + logf(s);
  float4 o0, o1;
  o0.x = logits[0] - lse; o0.y = logits[1] - lse; o0.z = logits[2] - lse; o0.w = logits[3] - lse;
  o1.x = logits[4] - lse; o1.y = logits[5] - lse; o1.z = logits[6] - lse; o1.w = logits[7] - lse;
  float4* o4 = (float4*)(out + (size_t)n * 8);
  o4[0] = o0; o4[1] = o1;
}

extern "C" void kernel_launch(void* const* d_in, const int* in_sizes, int n_in,
                              void* d_out, int out_size, void* d_ws, size_t ws_size,
                              hipStream_t stream) {
  const float* x   = (const float*)d_in[0];
  const int*   ei  = (const int*)d_in[1];
  const float* W1l = (const float*)d_in[2];
  const float* W1r = (const float*)d_in[3];
  const float* b1  = (const float*)d_in[4];
  const float* W2l = (const float*)d_in[5];
  const float* W2r = (const float*)d_in[6];
  const float* b2  = (const float*)d_in[7];
  const float* W3l = (const float*)d_in[8];
  const float* W3r = (const float*)d_in[9];
  const float* b3  = (const float*)d_in[10];
  const float* W4l = (const float*)d_in[11];
  const float* W4r = (const float*)d_in[12];
  const float* b4  = (const float*)d_in[13];

  const int N = in_sizes[0] / 64;   // 100000
  const int E = in_sizes[1] / 2;    // 1600000
  const size_t Ns = (size_t)N;
  const int B = (N + 127) >> 7;     // 782 buckets
  const int NBLK = (E + 8191) / 8192;  // 196

  // ---- workspace layout ----
  u16* ub      = (u16*)d_ws;
  u16* xb      = ub;                 // 64N
  u16* mean0b  = ub + 64 * Ns;       // 64N
  u16* h1b     = ub + 128 * Ns;      // 128N
  u16* mean1b  = ub + 256 * Ns;      // 128N
  u16* wt1     = ub + 384 * Ns;      // 16384
  u16* wt2     = wt1 + 16384;        // 32768
  u8*  h8      = (u8*)(wt2 + 32768); // 128N bytes (fp8 h1)
  u8*  x8      = h8 + 128 * Ns;      // 64N bytes (fp8 x)
  float* fb    = (float*)(x8 + 64 * Ns);
  float* p     = fb;                 // N
  float* q     = fb + Ns;            // N
  float* h3    = fb + 2 * Ns;        // N
  int* ib      = (int*)(fb + 3 * Ns);
  int* rowptr       = ib;                      // N+1
  int* gcur         = ib + (N + 1);            // 1024
  int* bucket_base  = gcur + 1024;             // 1025
  int* csr          = bucket_base + 1025;      // E
  u32* staging      = (u32*)(csr + E);         // 1024*BCAP

  float* out_rock   = (float*)d_out;            // N x 8
  float* out_scalar = (float*)d_out + 8 * Ns;   // N

  const int GG = (N + 127) / 128;
  const int total4 = N * 16;

  // ---- CSR build ----
  hipMemsetAsync(gcur, 0, 1024 * sizeof(int), stream);
  bucketize<<<NBLK, 512, 0, stream>>>(ei, gcur, staging, E, B);
  scan_tiny<<<1, 512, 0, stream>>>(gcur, bucket_base, rowptr, N, E);
  place<<<B, 256, 0, stream>>>(staging, bucket_base, rowptr, csr, N);

  // ---- conversions ----
  cvt_all<<<(total4 + 49152 + 255) / 256, 256, 0, stream>>>(
      x, xb, (u32*)x8, total4, W1l, W1r, W2l, W2r, wt1, wt2);

  // ---- layer 1 ----
  gather_mean_64f8<<<(N + 3) / 4, 256, 0, stream>>>(x8, rowptr, csr, mean0b, N);
  mfma_gemm<128, false><<<GG, 512, 0, stream>>>(
      mean0b, xb, wt1, b1, h1b, h8, nullptr, nullptr, nullptr, nullptr, N);

  // ---- layer 2 (+ fused p,q) ----
  gather_mean_128f8<<<(N + 3) / 4, 256, 0, stream>>>(h8, rowptr, csr, mean1b, N);
  mfma_gemm<256, true><<<GG, 512, 0, stream>>>(
      mean1b, h1b, wt2, b2, nullptr, nullptr, W3l, W3r, p, q, N);

  // ---- layer 3 (scalar) ----
  gather3_fused<<<(N + 255) / 256, 256, 0, stream>>>(p, rowptr, csr, q, b3, h3, out_scalar, N);

  // ---- layer 4 (scalar in, 8 out) ----
  gather4_fused<<<(N + 255) / 256, 256, 0, stream>>>(h3, rowptr, csr, W4l, W4r, b4, out_rock, N);
}

// Round 15
// 224.866 us; speedup vs baseline: 1.1718x; 1.0335x over previous
//
#include <hip/hip_runtime.h>
#include <hip/hip_bf16.h>
#include <math.h>

// GraphSAGE: 4 layers on N=100000 nodes, E=1600000 edges.
// Round 15: gather_mean_128f8 back to the measured-best shape (16 lanes x
// uint2 = 4 rows / 8 cache-lines per wave-instr, 48.3us in round 12).
// Rule learned: keep <=8 distinct cache lines per wave load instruction.

typedef unsigned char u8;
typedef unsigned short u16;
typedef unsigned int u32;
typedef __attribute__((ext_vector_type(2))) float f32x2;
typedef __attribute__((ext_vector_type(4))) float f32x4;
typedef __attribute__((ext_vector_type(8))) short s16x8;

#define BCAP 4096  // staging capacity per bucket (mean 2048, +45 sigma)

__device__ __forceinline__ float b2f(u16 u) {
  union { float f; u32 i; } v; v.i = ((u32)u) << 16; return v.f;
}
__device__ __forceinline__ u16 f2b(float f) {
  union { float f; u32 u; } v; v.f = f;
  u32 r = v.u + 0x7fffu + ((v.u >> 16) & 1u);   // RTN-even
  return (u16)(r >> 16);
}

// ---------------- CSR build ----------------
__global__ __launch_bounds__(512) void bucketize(const int* __restrict__ ei,
                                                 int* __restrict__ gcur,
                                                 u32* __restrict__ staging,
                                                 int E, int B) {
  __shared__ u32 vals[8192];
  __shared__ u16 bkt[8192];
  __shared__ int hist[1024], ofs[1024], curx[1024], gbase[1024];
  __shared__ int wsum[512];

  const int t = threadIdx.x;
  const int base = blockIdx.x * 8192;
  const int cnt = min(8192, E - base);

  for (int b = t; b < 1024; b += 512) hist[b] = 0;
  __syncthreads();

  for (int k = t; k < cnt; k += 512) {
    int d = ei[E + base + k];
    atomicAdd(&hist[d >> 7], 1);
  }
  __syncthreads();

  int a0 = hist[2 * t], a1 = hist[2 * t + 1];
  int s = a0 + a1;
  wsum[t] = s;
  __syncthreads();
  for (int off = 1; off < 512; off <<= 1) {
    int add = (t >= off) ? wsum[t - off] : 0;
    __syncthreads();
    wsum[t] += add;
    __syncthreads();
  }
  int excl = wsum[t] - s;
  ofs[2 * t] = excl;
  ofs[2 * t + 1] = excl + a0;
  __syncthreads();

  for (int b = t; b < B; b += 512) {
    int c = hist[b];
    gbase[b] = c ? atomicAdd(&gcur[b], c) : 0;
    curx[b] = ofs[b];
  }
  __syncthreads();

  for (int k = t; k < cnt; k += 512) {
    int sv = ei[base + k];
    int d = ei[E + base + k];
    int b = d >> 7;
    u32 val = (u32)sv | ((u32)(d & 127) << 17);
    int lpos = atomicAdd(&curx[b], 1);
    vals[lpos] = val;
    bkt[lpos] = (u16)b;
  }
  __syncthreads();

  for (int i = t; i < cnt; i += 512) {
    int b = bkt[i];
    staging[(size_t)b * BCAP + gbase[b] + (i - ofs[b])] = vals[i];
  }
}

__global__ __launch_bounds__(512) void scan_tiny(const int* __restrict__ gcur,
                                                 int* __restrict__ bucket_base,
                                                 int* __restrict__ rowptr,
                                                 int N, int E) {
  __shared__ int wsum[512];
  const int t = threadIdx.x;
  int c0 = gcur[2 * t];
  int c1 = gcur[2 * t + 1];
  int s = c0 + c1;
  wsum[t] = s;
  __syncthreads();
  for (int off = 1; off < 512; off <<= 1) {
    int add = (t >= off) ? wsum[t - off] : 0;
    __syncthreads();
    wsum[t] += add;
    __syncthreads();
  }
  int excl = wsum[t] - s;
  bucket_base[2 * t] = excl;
  bucket_base[2 * t + 1] = excl + c0;
  if (t == 511) bucket_base[1024] = wsum[511];
  if (t == 0) rowptr[N] = E;
}

__global__ __launch_bounds__(256) void place(const u32* __restrict__ staging,
                                             const int* __restrict__ bucket_base,
                                             int* __restrict__ rowptr,
                                             int* __restrict__ csr, int N) {
  __shared__ int cnt[128], excl[128], cur[128], sc[128];
  const int t = threadIdx.x;
  const int node0 = blockIdx.x << 7;
  const int nn = min(128, N - node0);
  if (t < 128) { cnt[t] = 0; cur[t] = 0; }
  __syncthreads();
  const int rstart = bucket_base[blockIdx.x];
  const int ec = bucket_base[blockIdx.x + 1] - rstart;
  const u32* slice = staging + (size_t)blockIdx.x * BCAP;
  for (int i = t; i < ec; i += 256)
    atomicAdd(&cnt[slice[i] >> 17], 1);
  __syncthreads();
  if (t < 128) sc[t] = cnt[t];
  __syncthreads();
  for (int off = 1; off < 128; off <<= 1) {
    int add = (t < 128 && t >= off) ? sc[t - off] : 0;
    __syncthreads();
    if (t < 128) sc[t] += add;
    __syncthreads();
  }
  if (t < 128) excl[t] = sc[t] - cnt[t];
  if (t < nn) rowptr[node0 + t] = rstart + excl[t];
  __syncthreads();
  for (int i = t; i < ec; i += 256) {
    u32 v = slice[i];
    int nl = v >> 17;
    int src = v & 0x1FFFF;
    int tk = atomicAdd(&cur[nl], 1);
    csr[rstart + excl[nl] + tk] = src;
  }
}

// ---------------- conversions (fused) ----------------
__global__ __launch_bounds__(256) void cvt_all(const float* __restrict__ x,
                                               u16* __restrict__ xb,
                                               u32* __restrict__ x8,  // fp8 x table
                                               int total4,
                                               const float* __restrict__ W1l,
                                               const float* __restrict__ W1r,
                                               const float* __restrict__ W2l,
                                               const float* __restrict__ W2r,
                                               u16* __restrict__ wt1,
                                               u16* __restrict__ wt2) {
  int i = blockIdx.x * 256 + threadIdx.x;
  if (i < total4) {
    float4 v = *(const float4*)(x + (size_t)i * 4);
    u32 lo = (u32)f2b(v.x) | ((u32)f2b(v.y) << 16);
    u32 hi = (u32)f2b(v.z) | ((u32)f2b(v.w) << 16);
    uint2 o; o.x = lo; o.y = hi;
    *(uint2*)(xb + (size_t)i * 4) = o;
    u32 pk = __builtin_amdgcn_cvt_pk_fp8_f32(v.x, v.y, 0, false);
    pk = __builtin_amdgcn_cvt_pk_fp8_f32(v.z, v.w, pk, true);
    x8[i] = pk;
    return;
  }
  int j = i - total4;
  if (j < 16384) {                 // Wt1: 128 x 128
    int jj = j >> 7, k = j & 127;
    float v = (k < 64) ? W1l[k * 128 + jj] : W1r[(k - 64) * 128 + jj];
    wt1[jj * 128 + k] = f2b(v);
  } else if (j < 16384 + 32768) {  // Wt2: 128 x 256
    int i2 = j - 16384;
    int jj = i2 >> 8, k = i2 & 255;
    float v = (k < 128) ? W2l[k * 128 + jj] : W2r[(k - 128) * 128 + jj];
    wt2[jj * 256 + k] = f2b(v);
  }
}

// ---------------- fp8 gather means ----------------
// accumulate 8 fp8 (uint2) into 4 f32x2
#define F8ACC8(v)                                                      \
  a0 += __builtin_amdgcn_cvt_pk_f32_fp8((v).x, false);                 \
  a1 += __builtin_amdgcn_cvt_pk_f32_fp8((v).x, true);                  \
  a2 += __builtin_amdgcn_cvt_pk_f32_fp8((v).y, false);                 \
  a3 += __builtin_amdgcn_cvt_pk_f32_fp8((v).y, true);

// layer-1: fp8 x rows (64B); 8 lanes x uint2 per row -> 8 rows / 8 lines per instr
__global__ __launch_bounds__(256) void gather_mean_64f8(const u8* __restrict__ x8,
                                                        const int* __restrict__ rowptr,
                                                        const int* __restrict__ csr,
                                                        u16* __restrict__ mean, int N) {
  int n = (blockIdx.x * 256 + threadIdx.x) >> 6;
  int lane = threadIdx.x & 63;
  int sub = lane >> 3;      // edge slot 0..7
  int ln = lane & 7;        // 8B chunk of 64B row (8 dims)
  if (n >= N) return;
  int s0 = rowptr[n], s1 = rowptr[n + 1];
  f32x2 a0 = (f32x2)(0.f), a1 = (f32x2)(0.f), a2 = (f32x2)(0.f), a3 = (f32x2)(0.f);
  int e = s0;
  for (; e + 16 <= s1; e += 16) {
    int i0 = csr[e + sub], i1 = csr[e + 8 + sub];
    uint2 v0 = *(const uint2*)(x8 + (size_t)i0 * 64 + ln * 8);
    uint2 v1 = *(const uint2*)(x8 + (size_t)i1 * 64 + ln * 8);
    F8ACC8(v0); F8ACC8(v1);
  }
  for (; e + 8 <= s1; e += 8) {
    int i0 = csr[e + sub];
    uint2 v0 = *(const uint2*)(x8 + (size_t)i0 * 64 + ln * 8);
    F8ACC8(v0);
  }
  int rem = s1 - e;
  if (sub < rem) {
    int i0 = csr[e + sub];
    uint2 v0 = *(const uint2*)(x8 + (size_t)i0 * 64 + ln * 8);
    F8ACC8(v0);
  }
#pragma unroll
  for (int off = 8; off < 64; off <<= 1) {
    a0.x += __shfl_xor(a0.x, off); a0.y += __shfl_xor(a0.y, off);
    a1.x += __shfl_xor(a1.x, off); a1.y += __shfl_xor(a1.y, off);
    a2.x += __shfl_xor(a2.x, off); a2.y += __shfl_xor(a2.y, off);
    a3.x += __shfl_xor(a3.x, off); a3.y += __shfl_xor(a3.y, off);
  }
  if (sub == 0) {
    int c = s1 - s0;
    float inv = c > 0 ? 1.f / (float)c : 0.f;
    uint4 o;
    o.x = (u32)f2b(a0.x * inv) | ((u32)f2b(a0.y * inv) << 16);
    o.y = (u32)f2b(a1.x * inv) | ((u32)f2b(a1.y * inv) << 16);
    o.z = (u32)f2b(a2.x * inv) | ((u32)f2b(a2.y * inv) << 16);
    o.w = (u32)f2b(a3.x * inv) | ((u32)f2b(a3.y * inv) << 16);
    *(uint4*)(mean + (size_t)n * 64 + ln * 8) = o;
  }
}

// layer-2: fp8 h1 rows (128B); 16 lanes x uint2 per row -> 4 rows / 8 lines per
// instr (round-12 measured-best: 48.3us).
__global__ __launch_bounds__(256) void gather_mean_128f8(const u8* __restrict__ h8,
                                                         const int* __restrict__ rowptr,
                                                         const int* __restrict__ csr,
                                                         u16* __restrict__ mean, int N) {
  int n = (blockIdx.x * 256 + threadIdx.x) >> 6;
  int lane = threadIdx.x & 63;
  int sub = lane >> 4;      // edge slot 0..3
  int ln = lane & 15;       // 8B chunk of 128B row (8 dims)
  if (n >= N) return;
  int s0 = rowptr[n], s1 = rowptr[n + 1];
  f32x2 a0 = (f32x2)(0.f), a1 = (f32x2)(0.f), a2 = (f32x2)(0.f), a3 = (f32x2)(0.f);
  int e = s0;
  for (; e + 16 <= s1; e += 16) {   // 16 edges in flight (4 loads/thread)
    int i0 = csr[e + sub], i1 = csr[e + 4 + sub];
    int i2 = csr[e + 8 + sub], i3 = csr[e + 12 + sub];
    uint2 v0 = *(const uint2*)(h8 + (size_t)i0 * 128 + ln * 8);
    uint2 v1 = *(const uint2*)(h8 + (size_t)i1 * 128 + ln * 8);
    uint2 v2 = *(const uint2*)(h8 + (size_t)i2 * 128 + ln * 8);
    uint2 v3 = *(const uint2*)(h8 + (size_t)i3 * 128 + ln * 8);
    F8ACC8(v0); F8ACC8(v1); F8ACC8(v2); F8ACC8(v3);
  }
  for (; e + 4 <= s1; e += 4) {
    int i0 = csr[e + sub];
    uint2 v0 = *(const uint2*)(h8 + (size_t)i0 * 128 + ln * 8);
    F8ACC8(v0);
  }
  int rem = s1 - e;
  if (sub < rem) {
    int i0 = csr[e + sub];
    uint2 v0 = *(const uint2*)(h8 + (size_t)i0 * 128 + ln * 8);
    F8ACC8(v0);
  }
#pragma unroll
  for (int off = 16; off < 64; off <<= 1) {
    a0.x += __shfl_xor(a0.x, off); a0.y += __shfl_xor(a0.y, off);
    a1.x += __shfl_xor(a1.x, off); a1.y += __shfl_xor(a1.y, off);
    a2.x += __shfl_xor(a2.x, off); a2.y += __shfl_xor(a2.y, off);
    a3.x += __shfl_xor(a3.x, off); a3.y += __shfl_xor(a3.y, off);
  }
  if (sub == 0) {
    int c = s1 - s0;
    float inv = c > 0 ? 1.f / (float)c : 0.f;
    uint4 o;
    o.x = (u32)f2b(a0.x * inv) | ((u32)f2b(a0.y * inv) << 16);
    o.y = (u32)f2b(a1.x * inv) | ((u32)f2b(a1.y * inv) << 16);
    o.z = (u32)f2b(a2.x * inv) | ((u32)f2b(a2.y * inv) << 16);
    o.w = (u32)f2b(a3.x * inv) | ((u32)f2b(a3.y * inv) << 16);
    *(uint4*)(mean + (size_t)n * 128 + ln * 8) = o;
  }
}

// ---------------- MFMA GEMM ----------------
// !FINAL: writes h1 bf16 + fp8 side copy. FINAL: fuses p,q projection.
template<int K2, bool FINAL>
__global__ __launch_bounds__(512) void mfma_gemm(
    const u16* __restrict__ meanb, const u16* __restrict__ prevb,
    const u16* __restrict__ wt,    // [128][K2] bf16 (pre-transposed)
    const float* __restrict__ bias,
    u16* __restrict__ hout, u8* __restrict__ hout8,
    const float* __restrict__ W3l, const float* __restrict__ W3r,
    float* __restrict__ outp, float* __restrict__ outq, int N) {
  constexpr int KH = K2 / 2;
  constexpr int NC = K2 / 8;
  __shared__ __align__(16) u16 Albs[128 * K2];
  __shared__ __align__(16) u16 Wlds[128 * K2];

  const int t = threadIdx.x;
  const int tile = blockIdx.x * 128;

  for (int i = t; i < 128 * NC; i += 512) {
    int j = i / NC, c = i - j * NC;
    uint4 v = *(const uint4*)(wt + (size_t)j * K2 + c * 8);
    *(uint4*)(Wlds + j * K2 + ((c ^ (j & 7)) << 3)) = v;
  }
  for (int i = t; i < 128 * NC; i += 512) {
    int r = i / NC, c = i - r * NC;
    int node = tile + r;
    uint4 v; v.x = 0; v.y = 0; v.z = 0; v.w = 0;
    if (node < N) {
      int k0 = c * 8;
      v = (k0 < KH) ? *(const uint4*)(meanb + (size_t)node * KH + k0)
                    : *(const uint4*)(prevb + (size_t)node * KH + (k0 - KH));
    }
    *(uint4*)(Albs + r * K2 + ((c ^ (r & 7)) << 3)) = v;
  }
  __syncthreads();

  const int lane = t & 63;
  const int wid = t >> 6;
  const int wm = wid >> 1, wn = wid & 1;
  const int er = lane & 15;
  const int kg = lane >> 4;

  f32x4 acc[2][4];
#pragma unroll
  for (int mi = 0; mi < 2; ++mi)
#pragma unroll
    for (int ni = 0; ni < 4; ++ni) acc[mi][ni] = (f32x4)(0.f);

#pragma unroll
  for (int ks = 0; ks < K2 / 32; ++ks) {
    int cidx = ks * 4 + kg;
    s16x8 a[2], b[4];
#pragma unroll
    for (int mi = 0; mi < 2; ++mi) {
      int row = wm * 32 + mi * 16 + er;
      a[mi] = *(const s16x8*)(Albs + row * K2 + ((cidx ^ (row & 7)) << 3));
    }
#pragma unroll
    for (int ni = 0; ni < 4; ++ni) {
      int col = wn * 64 + ni * 16 + er;
      b[ni] = *(const s16x8*)(Wlds + col * K2 + ((cidx ^ (col & 7)) << 3));
    }
#pragma unroll
    for (int mi = 0; mi < 2; ++mi)
#pragma unroll
      for (int ni = 0; ni < 4; ++ni)
        acc[mi][ni] = __builtin_amdgcn_mfma_f32_16x16x32_bf16(a[mi], b[ni], acc[mi][ni], 0, 0, 0);
  }

  if constexpr (!FINAL) {
#pragma unroll
    for (int mi = 0; mi < 2; ++mi) {
#pragma unroll
      for (int ni = 0; ni < 4; ++ni) {
        int col = wn * 64 + ni * 16 + er;
        float bv = bias[col];
#pragma unroll
        for (int r = 0; r < 4; ++r) {
          int node = tile + wm * 32 + mi * 16 + kg * 4 + r;
          if (node < N) {
            float v = acc[mi][ni][r] + bv;
            v = v > 0.f ? v : 0.f;
            hout[(size_t)node * 128 + col] = f2b(v);
            u32 pk = __builtin_amdgcn_cvt_pk_fp8_f32(v, v, 0, false);
            hout8[(size_t)node * 128 + col] = (u8)pk;
          }
        }
      }
    }
  } else {
    __shared__ float p_lds[128][2], q_lds[128][2];
    float wl[4], wr[4], bv[4];
#pragma unroll
    for (int ni = 0; ni < 4; ++ni) {
      int col = wn * 64 + ni * 16 + er;
      wl[ni] = W3l[col]; wr[ni] = W3r[col]; bv[ni] = bias[col];
    }
#pragma unroll
    for (int mi = 0; mi < 2; ++mi) {
#pragma unroll
      for (int r = 0; r < 4; ++r) {
        float pv = 0.f, qv = 0.f;
#pragma unroll
        for (int ni = 0; ni < 4; ++ni) {
          float v = acc[mi][ni][r] + bv[ni];
          v = v > 0.f ? v : 0.f;
          pv = fmaf(v, wl[ni], pv);
          qv = fmaf(v, wr[ni], qv);
        }
#pragma unroll
        for (int off = 1; off < 16; off <<= 1) {
          pv += __shfl_xor(pv, off);
          qv += __shfl_xor(qv, off);
        }
        if (er == 0) {
          int nl = wm * 32 + mi * 16 + kg * 4 + r;
          p_lds[nl][wn] = pv;
          q_lds[nl][wn] = qv;
        }
      }
    }
    __syncthreads();
    if (t < 128) {
      int node = tile + t;
      if (node < N) {
        outp[node] = p_lds[t][0] + p_lds[t][1];
        outq[node] = q_lds[t][0] + q_lds[t][1];
      }
    }
  }
}

// ---------------- layer 3 fused: h3 = mean_e(p) + q + b3 ; out_scalar ----------------
__global__ __launch_bounds__(256) void gather3_fused(const float* __restrict__ p,
                                                     const int* __restrict__ rowptr,
                                                     const int* __restrict__ csr,
                                                     const float* __restrict__ q,
                                                     const float* __restrict__ b3,
                                                     float* __restrict__ h3,
                                                     float* __restrict__ out_scalar, int N) {
  int n = blockIdx.x * 256 + threadIdx.x;
  if (n >= N) return;
  int s0 = rowptr[n], s1 = rowptr[n + 1];
  float a = 0.f;
  for (int e = s0; e < s1; ++e) a += p[csr[e]];
  int c = s1 - s0;
  float inv = c > 0 ? 1.f / (float)c : 0.f;
  float v = a * inv + q[n] + b3[0];
  h3[n] = v;
  out_scalar[n] = v;
}

// ---------------- layer 4 fused: mean_e(h3) -> logits -> log_softmax ----------------
__global__ __launch_bounds__(256) void gather4_fused(const float* __restrict__ h3,
                                                     const int* __restrict__ rowptr,
                                                     const int* __restrict__ csr,
                                                     const float* __restrict__ W4l,
                                                     const float* __restrict__ W4r,
                                                     const float* __restrict__ b4,
                                                     float* __restrict__ out, int N) {
  int n = blockIdx.x * 256 + threadIdx.x;
  if (n >= N) return;
  int s0 = rowptr[n], s1 = rowptr[n + 1];
  float a = 0.f;
  for (int e = s0; e < s1; ++e) a += h3[csr[e]];
  int c = s1 - s0;
  float inv = c > 0 ? 1.f / (float)c : 0.f;
  float m = a * inv;
  float hv = h3[n];
  float logits[8];
  float mx = -1e30f;
#pragma unroll
  for (int jj = 0; jj < 8; ++jj) {
    float v = m * W4l[jj] + hv * W4r[jj] + b4[jj];
    logits[jj] = v;
    mx = v > mx ? v : mx;
  }
  float s = 0.f;
#pragma unroll
  for (int jj = 0; jj < 8; ++jj) s += expf(logits[jj] - mx);
  float lse = mx + logf(s);
  float4 o0, o1;
  o0.x = logits[0] - lse; o0.y = logits[1] - lse; o0.z = logits[2] - lse; o0.w = logits[3] - lse;
  o1.x = logits[4] - lse; o1.y = logits[5] - lse; o1.z = logits[6] - lse; o1.w = logits[7] - lse;
  float4* o4 = (float4*)(out + (size_t)n * 8);
  o4[0] = o0; o4[1] = o1;
}

extern "C" void kernel_launch(void* const* d_in, const int* in_sizes, int n_in,
                              void* d_out, int out_size, void* d_ws, size_t ws_size,
                              hipStream_t stream) {
  const float* x   = (const float*)d_in[0];
  const int*   ei  = (const int*)d_in[1];
  const float* W1l = (const float*)d_in[2];
  const float* W1r = (const float*)d_in[3];
  const float* b1  = (const float*)d_in[4];
  const float* W2l = (const float*)d_in[5];
  const float* W2r = (const float*)d_in[6];
  const float* b2  = (const float*)d_in[7];
  const float* W3l = (const float*)d_in[8];
  const float* W3r = (const float*)d_in[9];
  const float* b3  = (const float*)d_in[10];
  const float* W4l = (const float*)d_in[11];
  const float* W4r = (const float*)d_in[12];
  const float* b4  = (const float*)d_in[13];

  const int N = in_sizes[0] / 64;   // 100000
  const int E = in_sizes[1] / 2;    // 1600000
  const size_t Ns = (size_t)N;
  const int B = (N + 127) >> 7;     // 782 buckets
  const int NBLK = (E + 8191) / 8192;  // 196

  // ---- workspace layout ----
  u16* ub      = (u16*)d_ws;
  u16* xb      = ub;                 // 64N
  u16* mean0b  = ub + 64 * Ns;       // 64N
  u16* h1b     = ub + 128 * Ns;      // 128N
  u16* mean1b  = ub + 256 * Ns;      // 128N
  u16* wt1     = ub + 384 * Ns;      // 16384
  u16* wt2     = wt1 + 16384;        // 32768
  u8*  h8      = (u8*)(wt2 + 32768); // 128N bytes (fp8 h1)
  u8*  x8      = h8 + 128 * Ns;      // 64N bytes (fp8 x)
  float* fb    = (float*)(x8 + 64 * Ns);
  float* p     = fb;                 // N
  float* q     = fb + Ns;            // N
  float* h3    = fb + 2 * Ns;        // N
  int* ib      = (int*)(fb + 3 * Ns);
  int* rowptr       = ib;                      // N+1
  int* gcur         = ib + (N + 1);            // 1024
  int* bucket_base  = gcur + 1024;             // 1025
  int* csr          = bucket_base + 1025;      // E
  u32* staging      = (u32*)(csr + E);         // 1024*BCAP

  float* out_rock   = (float*)d_out;            // N x 8
  float* out_scalar = (float*)d_out + 8 * Ns;   // N

  const int GG = (N + 127) / 128;
  const int total4 = N * 16;

  // ---- CSR build ----
  hipMemsetAsync(gcur, 0, 1024 * sizeof(int), stream);
  bucketize<<<NBLK, 512, 0, stream>>>(ei, gcur, staging, E, B);
  scan_tiny<<<1, 512, 0, stream>>>(gcur, bucket_base, rowptr, N, E);
  place<<<B, 256, 0, stream>>>(staging, bucket_base, rowptr, csr, N);

  // ---- conversions ----
  cvt_all<<<(total4 + 49152 + 255) / 256, 256, 0, stream>>>(
      x, xb, (u32*)x8, total4, W1l, W1r, W2l, W2r, wt1, wt2);

  // ---- layer 1 ----
  gather_mean_64f8<<<(N + 3) / 4, 256, 0, stream>>>(x8, rowptr, csr, mean0b, N);
  mfma_gemm<128, false><<<GG, 512, 0, stream>>>(
      mean0b, xb, wt1, b1, h1b, h8, nullptr, nullptr, nullptr, nullptr, N);

  // ---- layer 2 (+ fused p,q) ----
  gather_mean_128f8<<<(N + 3) / 4, 256, 0, stream>>>(h8, rowptr, csr, mean1b, N);
  mfma_gemm<256, true><<<GG, 512, 0, stream>>>(
      mean1b, h1b, wt2, b2, nullptr, nullptr, W3l, W3r, p, q, N);

  // ---- layer 3 (scalar) ----
  gather3_fused<<<(N + 255) / 256, 256, 0, stream>>>(p, rowptr, csr, q, b3, h3, out_scalar, N);

  // ---- layer 4 (scalar in, 8 out) ----
  gather4_fused<<<(N + 255) / 256, 256, 0, stream>>>(h3, rowptr, csr, W4l, W4r, b4, out_rock, N);
}